// Round 2
// baseline (80.694 us; speedup 1.0000x reference)
//
#include <hip/hip_runtime.h>

#define STEP 10
#define NCH  256                 // 128*2 flattened channels = DP "batches"
#define CSCL (-144.2695041f)     // -(1/GAMMA)*log2(e): scale into log2 domain
#define GLN2 (-0.00693147181f)   // -GAMMA*ln(2) == 1/CSCL (to 7e-10 rel)
#define BIGP (-1.442695041e12f)  // 1e10 * CSCL : boundary "BIG" in scaled domain
#define YOFF 256                 // pad so idx = YOFF + (s-2-2t) >= 0 for t<=127
#define YLDS 768                 // covers YOFF + 2N + 3 for N <= 253

// exp2/log2 via raw ISA (no fast-math dependence)
__device__ __forceinline__ float fexp2(float x){ float r; asm("v_exp_f32 %0, %1" : "=v"(r) : "v"(x)); return r; }
__device__ __forceinline__ float flog2(float x){ float r; asm("v_log_f32 %0, %1" : "=v"(r) : "v"(x)); return r; }

// One soft-DTW cell in the scaled domain R' = R*CSCL (CSCL < 0):
//   R'new = d^2*CSCL + log2(1 + 2^(lo-m) + 2^(md-m)) + m
__device__ __forceinline__ float dpcell(float up2, float up, float left,
                                        float xv, float yv, int jj, unsigned nlim) {
    float m  = fmaxf(fmaxf(up2, up), left);            // v_max3_f32
    float lo = fminf(fminf(up2, up), left);            // v_min3_f32
    float md = __builtin_amdgcn_fmed3f(up2, up, left); // v_med3_f32
    float e  = fexp2(lo - m) + fexp2(md - m) + 1.0f;
    float ls = flog2(e) + m;
    float d  = xv - yv;
    float v  = fmaf(d * CSCL, d, ls);
    return ((unsigned)jj < nlim) ? v : BIGP;           // j in [1,N] && row valid
}

// TWO waves (128 lanes) per batch, 2 rows per thread (i0 = 2t+1).
// Anti-diagonal wavefront; in-wave neighbor handoff via __shfl_up, cross-wave
// handoff (t=63 -> t=64) via a parity-double-buffered LDS slot + one
// __syncthreads per diagonal. Cell math identical to the 1-wave version
// (bit-identical results); per-wave issue per diagonal is halved.
__global__ __launch_bounds__(128)
void softdtw_wave(const float* __restrict__ x, const float* __restrict__ y,
                  float* __restrict__ ws, int N) {
    const int b = blockIdx.x;
    const int t = threadIdx.x;          // 0..127
    const int l = t & 63;               // lane within wave
    const int w = t >> 6;               // wave id (0 or 1)

    __shared__ __align__(16) float YsP[YLDS];
    __shared__ float Hs[2];             // cross-wave boundary, parity buffered
    for (int j = t; j < YLDS; j += 128) YsP[j] = 0.0f;
    __syncthreads();
    for (int j = t; j < N; j += 128) YsP[YOFF + j] = y[j * STEP * NCH + b];
    __syncthreads();

    const int i0 = 2 * t + 1;           // first row owned by this thread
    float xv0 = (i0     <= N) ? x[(i0 - 1) * STEP * NCH + b] : 0.f;
    float xv1 = (i0 + 1 <= N) ? x[(i0    ) * STEP * NCH + b] : 0.f;
    const unsigned nl0 = (i0     <= N) ? (unsigned)N : 0u;
    const unsigned nl1 = (i0 + 1 <= N) ? (unsigned)N : 0u;

    // scaled DP state: sp* = diag s-1, sq0 = diag s-2 (row i0 only)
    float sp0 = BIGP, sp1 = BIGP, sq0 = BIGP;
    // neighbor-row (i0-1) values: bp = diag s-1, bq = diag s-2 (bq(s)=bp(s-1))
    float bp = BIGP;
    float bq = (t == 0) ? 0.0f : BIGP;  // R'[0][0] = 0 enters at s=2
    // y window: w0 = Y[jm1] (c0), w1 = Y[jm1-1] (c1) = previous diag's w0
    float w0 = 0.f, w1 = 0.f;

    int jm1 = -2 * t;                   // (j-1) for row i0 at s=2
    const int smax = 2 * N;

    // lane-relative float2 pointer (8B aligned: YOFF even, offset -2t even)
    const float2* yp2 = (const float2*)(YsP + YOFF) - t;
    float2 yb = yp2[0];                 // y values for diagonals s, s+1

    #define DSTEP(WNEW, JC, PAR) do {                                     \
        w1 = w0; w0 = (WNEW);                                             \
        float c1  = dpcell(sq0, sp0, sp1, xv1, w1, (JC) - 1, nl1);        \
        float c0  = dpcell(bq,  bp,  sp0, xv0, w0, (JC),     nl0);        \
        float bpn = __shfl_up(c1, 1, 64);                                 \
        if (t == 63) Hs[PAR] = c1;                                        \
        __syncthreads();                                                  \
        float hb = Hs[PAR];                                               \
        sq0 = sp0; sp0 = c0; sp1 = c1;                                    \
        bq = bp;                                                          \
        bp = (l == 0) ? ((w == 0) ? BIGP : hb) : bpn;                     \
    } while (0)

    int s = 2, g = 0;
    for (; s + 1 <= smax; s += 2, ++g) {
        float2 ybn = yp2[g + 1];        // prefetch next 2 diagonals' y values
        DSTEP(yb.x, jm1,     0);
        DSTEP(yb.y, jm1 + 1, 1);
        yb = ybn;
        jm1 += 2;
    }
    if (s <= smax) DSTEP(yb.x, jm1, 0); // odd tail diagonal
    #undef DSTEP

    // R[N][N] sits on diag 2N at row N = i0 or i0+1; un-scale on the way out
    if      (i0     == N) ws[b] = sp0 * GLN2;
    else if (i0 + 1 == N) ws[b] = sp1 * GLN2;
}

// Deterministic 256 -> 1 reduction (shuffle within wave64, LDS across 4 waves)
__global__ __launch_bounds__(256)
void reduce256(const float* __restrict__ ws, float* __restrict__ out) {
    const int tid = threadIdx.x;
    float v = ws[tid];
    #pragma unroll
    for (int off = 32; off > 0; off >>= 1)
        v += __shfl_down(v, off, 64);
    __shared__ float partial[4];
    if ((tid & 63) == 0) partial[tid >> 6] = v;
    __syncthreads();
    if (tid == 0) out[0] = (partial[0] + partial[1]) + (partial[2] + partial[3]);
}

extern "C" void kernel_launch(void* const* d_in, const int* in_sizes, int n_in,
                              void* d_out, int out_size, void* d_ws, size_t ws_size,
                              hipStream_t stream) {
    const float* x = (const float*)d_in[0];
    const float* y = (const float*)d_in[1];
    float* out = (float*)d_out;
    float* ws  = (float*)d_ws;

    const int T = in_sizes[0] / NCH;            // 2048 frames
    const int L = (T + STEP - 1) / STEP;        // 205 subsampled frames

    softdtw_wave<<<dim3(NCH), dim3(128), 0, stream>>>(x, y, ws, L);
    reduce256<<<dim3(1), dim3(256), 0, stream>>>(ws, out);
}

// Round 3
// 57.978 us; speedup vs baseline: 1.3918x; 1.3918x over previous
//
#include <hip/hip_runtime.h>

#define STEP 10
#define NCH  256                 // 128*2 flattened channels = DP "batches"
#define CSCL (-144.2695041f)     // -(1/GAMMA)*log2(e): scale into log2 domain
#define GLN2 (-0.00693147181f)   // -GAMMA*ln(2) == 1/CSCL (to 7e-10 rel)
#define BIGP (-1.442695041e12f)  // 1e10 * CSCL : boundary "BIG" in scaled domain
#define YOFF 256                 // pad: idx = YOFF + (s-2-2t) >= 0 for all t
#define YLDS 768
#define BNDSZ 424                // row-128 boundary value per diagonal s
#define LAGG 17                  // wave-1 lag in groups (17*8 = 136 >= 129 diags)

// exp2/log2 via raw ISA (no fast-math dependence)
__device__ __forceinline__ float fexp2(float x){ float r; asm("v_exp_f32 %0, %1" : "=v"(r) : "v"(x)); return r; }
__device__ __forceinline__ float flog2(float x){ float r; asm("v_log_f32 %0, %1" : "=v"(r) : "v"(x)); return r; }

// Soft-DTW cell in the scaled domain R' = R*CSCL (CSCL < 0). No boundary mask:
// invalid cells self-perpetuate at ~BIGP (drift << 1e12) and underflow to a
// contribution of exactly 0.0f in any valid cell's exp2 — bit-identical to
// explicit masking.
__device__ __forceinline__ float dpcell(float up2, float up, float left,
                                        float xv, float yv) {
    float m  = fmaxf(fmaxf(up2, up), left);            // v_max3_f32
    float lo = fminf(fminf(up2, up), left);            // v_min3_f32
    float md = __builtin_amdgcn_fmed3f(up2, up, left); // v_med3_f32
    float e  = fexp2(lo - m) + fexp2(md - m) + 1.0f;
    float ls = flog2(e) + m;
    float d  = xv - yv;
    return fmaf(d * CSCL, d, ls);
}

// Two waves per batch, 2 rows/thread. Wave 0 owns rows 1..128, wave 1 rows
// 129..256 and runs LAGG*8 diagonals behind, consuming the row-128 boundary
// from LDS (written >= 8 diagonals earlier — never latency-exposed, never
// racy: per-group read range [8k-6, 8k+1] vs write range [8k+2, 8k+9]).
// One __syncthreads per 8 diagonals.
__global__ __launch_bounds__(128)
void softdtw_wave(const float* __restrict__ x, const float* __restrict__ y,
                  float* __restrict__ ws, int N) {
    const int b = blockIdx.x;
    const int t = threadIdx.x;          // 0..127
    const int l = t & 63;               // lane within wave
    const bool isw0 = (t < 64);

    __shared__ __align__(16) float YsP[YLDS];
    __shared__ float bnd[BNDSZ];
    for (int j = t; j < YLDS;  j += 128) YsP[j] = 0.0f;
    for (int j = t; j < BNDSZ; j += 128) bnd[j] = BIGP;
    __syncthreads();
    for (int j = t; j < N; j += 128) YsP[YOFF + j] = y[j * STEP * NCH + b];
    __syncthreads();

    const int i0 = 2 * t + 1;           // rows i0, i0+1
    float xv0 = (i0     <= N) ? x[(i0 - 1) * STEP * NCH + b] : 0.f;
    float xv1 = (i0 + 1 <= N) ? x[(i0    ) * STEP * NCH + b] : 0.f;

    // scaled DP state: sp* = diag s-1, sq0 = diag s-2 (row i0)
    float sp0 = BIGP, sp1 = BIGP, sq0 = BIGP;
    float bp  = BIGP;                   // carried shfl'd neighbor (non-lane0)
    float bq  = (t == 0) ? 0.0f : BIGP; // R'[0][0] seed enters at s=2
    float w0v = 0.f, w1v = 0.f;         // y window: Y[jm1], Y[jm1-1]

    const int smax = 2 * N;
    const int NG0  = (127 + N + 7) >> 3;        // wave-0 groups (diags 2..128+N)
    const int NG1  = (smax - 129 + 7) >> 3;     // wave-1 groups (diags 130..2N)
    const int NGRP = (NG0 > LAGG + NG1) ? NG0 : (LAGG + NG1);

    #define STEPJ(WNEW, HJ, J) do {                                   \
        w1v = w0v; w0v = (WNEW);                                      \
        float c1  = dpcell(sq0, sp0, sp1, xv1, w1v);                  \
        float bpu = (l == 0) ? (HJ) : bp;                             \
        float c0  = dpcell(bq, bpu, sp0, xv0, w0v);                   \
        float bpn = __shfl_up(c1, 1, 64);                             \
        if (isw0 && l == 63) bnd[sb + (J)] = c1;                      \
        sq0 = sp0; sp0 = c0; sp1 = c1;                                \
        bq = bpu; bp = bpn;                                           \
        if (sb + (J) == smax) {                                       \
            if      (i0     == N) ws[b] = sp0 * GLN2;                 \
            else if (i0 + 1 == N) ws[b] = sp1 * GLN2;                 \
        }                                                             \
    } while (0)

    for (int k = 0; k < NGRP; ++k) {
        __syncthreads();                 // makes wave-0's group-(k-1) writes visible
        const int  m   = isw0 ? k : (k - LAGG);
        const bool act = isw0 ? (k < NG0) : (m >= 0 && m < NG1);
        if (act) {
            const int sb = (isw0 ? 2 : 130) + (m << 3);   // first diag of group
            // y for steps 0..7: Y[sb-2-2t + j] (8B-aligned float2 reads)
            const float2* yp = (const float2*)(YsP + YOFF + (sb - 2)) - t;
            float2 ya = yp[0], yb = yp[1], yc = yp[2], yd = yp[3];
            // boundary (row 128) values for lane 0 of wave 1; BIGP row-0 wall
            float h0,h1,h2,h3,h4,h5,h6,h7;
            if (isw0) { h0=h1=h2=h3=h4=h5=h6=h7 = BIGP; }
            else { h0=bnd[sb+0]; h1=bnd[sb+1]; h2=bnd[sb+2]; h3=bnd[sb+3];
                   h4=bnd[sb+4]; h5=bnd[sb+5]; h6=bnd[sb+6]; h7=bnd[sb+7]; }
            STEPJ(ya.x, h0, 0); STEPJ(ya.y, h1, 1);
            STEPJ(yb.x, h2, 2); STEPJ(yb.y, h3, 3);
            STEPJ(yc.x, h4, 4); STEPJ(yc.y, h5, 5);
            STEPJ(yd.x, h6, 6); STEPJ(yd.y, h7, 7);
        }
    }
    #undef STEPJ
}

// Deterministic 256 -> 1 reduction (shuffle within wave64, LDS across 4 waves)
__global__ __launch_bounds__(256)
void reduce256(const float* __restrict__ ws, float* __restrict__ out) {
    const int tid = threadIdx.x;
    float v = ws[tid];
    #pragma unroll
    for (int off = 32; off > 0; off >>= 1)
        v += __shfl_down(v, off, 64);
    __shared__ float partial[4];
    if ((tid & 63) == 0) partial[tid >> 6] = v;
    __syncthreads();
    if (tid == 0) out[0] = (partial[0] + partial[1]) + (partial[2] + partial[3]);
}

extern "C" void kernel_launch(void* const* d_in, const int* in_sizes, int n_in,
                              void* d_out, int out_size, void* d_ws, size_t ws_size,
                              hipStream_t stream) {
    const float* x = (const float*)d_in[0];
    const float* y = (const float*)d_in[1];
    float* out = (float*)d_out;
    float* ws  = (float*)d_ws;

    const int T = in_sizes[0] / NCH;            // 2048 frames
    const int L = (T + STEP - 1) / STEP;        // 205 subsampled frames

    softdtw_wave<<<dim3(NCH), dim3(128), 0, stream>>>(x, y, ws, L);
    reduce256<<<dim3(1), dim3(256), 0, stream>>>(ws, out);
}